// Round 12
// baseline (133.744 us; speedup 1.0000x reference)
//
#include <hip/hip_runtime.h>
#include <hip/hip_bf16.h>
#include <math.h>

#define BB 2
#define SS 4096
#define HH 768
#define NHEADS 12
#define MTOT (BB*SS)     // 8192
#define NQKV (3*HH)      // 2304

typedef _Float16 f16;
typedef __attribute__((ext_vector_type(8))) _Float16 f16x8;
typedef __attribute__((ext_vector_type(4))) _Float16 f16x4;
typedef __attribute__((ext_vector_type(4))) float f32x4;

__device__ __forceinline__ void gld_lds16(const void* g, void* l) {
  __builtin_amdgcn_global_load_lds(
      (const __attribute__((address_space(1))) unsigned int*)g,
      (__attribute__((address_space(3))) unsigned int*)l, 16, 0, 0);
}

// ---------------- f32 -> f16 convert -------------------------------------
__global__ __launch_bounds__(256)
void cvt_kernel(const float* __restrict__ src, f16* __restrict__ dst, int n4) {
  int i = blockIdx.x * 256 + threadIdx.x;
  if (i >= n4) return;
  float4 v = reinterpret_cast<const float4*>(src)[i];
  f16x4 o;
  o[0] = (f16)v.x; o[1] = (f16)v.y; o[2] = (f16)v.z; o[3] = (f16)v.w;
  reinterpret_cast<f16x4*>(dst)[i] = o;
}

// ---------------- RoPE cos/sin table (f64 phase) -------------------------
__global__ void rope_table_kernel(float* __restrict__ ctab, float* __restrict__ stab) {
  int idx = blockIdx.x * 256 + threadIdx.x;   // 4096*32
  if (idx >= SS * 32) return;
  int s = idx >> 5;
  int j = idx & 31;
  const double r = 0.7498942093324559;  // 10000^(-1/32)
  double inv = 1.0;
  for (int t = 0; t < j; ++t) inv *= r;
  double ph = (double)s * inv;
  const double TWO_PI = 6.283185307179586;
  double red = ph - TWO_PI * floor(ph / TWO_PI);
  float rf = (float)red;
  ctab[idx] = cosf(rf);
  stab[idx] = sinf(rf);
}

// ======== GEMM1: 256x256 tile, 8 waves, BK=64, phase-split pipeline ======
// qkv = hs16 * Wqkv^T with fused RoPE/scale epilogue -> q/k/v f16.
// M=8192 N=2304 K=768 hardcoded. 128 KB LDS, counted vmcnt(2)/K-tile.
// Chunk swizzle (verified R9/R10): global 16B-chunk g of 8 per 128B row
// stored at phys p = g ^ (row&7); read applies same XOR.
__global__ __launch_bounds__(512)
void gemm1_256(const f16* __restrict__ A, const f16* __restrict__ Bw,
               f16* __restrict__ Oq, f16* __restrict__ Ok, f16* __restrict__ Ov,
               const int* __restrict__ pos,
               const float* __restrict__ ctab, const float* __restrict__ stab) {
  __shared__ __align__(16) f16 As[2][256][64];  // 64 KB
  __shared__ __align__(16) f16 Bs[2][256][64];  // 64 KB
  const int K = HH;
  const int tid = threadIdx.x;         // 0..511
  const int lane = tid & 63;
  const int w = tid >> 6;              // 0..7
  const int wr = w >> 2, wc = w & 3;   // 2 x 4 wave grid

  // M-chunked XCD map: grid 288 = 8 xcd * 36; 4 M-tiles per XCD chunk
  const int bid = blockIdx.x;
  const int xcd = bid & 7;
  const int idx = bid >> 3;            // 0..35
  const int bm = (xcd * 4 + (idx & 3)) * 256;
  const int bn = (idx >> 2) * 256;     // 0..8 * 256

  f32x4 acc[8][4] = {};

  const int trow = tid >> 3;           // 0..63 staging row-sub
  const int gsw = (tid & 7) ^ (trow & 7);
  const int fr = lane & 15;
  const int g16 = lane >> 4;

  // stage half ph of K-tile at k0 into slot: ph 0,1 = A halves; 2,3 = B.
  // Exactly 2 gld_lds per thread per call.
  auto stage = [&](int slot, int ph, int k0) {
    const f16* src = (ph < 2) ? A : Bw;
    const int hh = ph & 1;
    const int rbase = ((ph < 2) ? bm : bn) + hh * 128;
    char* dstbase = ((ph < 2) ? (char*)&As[slot][0][0] : (char*)&Bs[slot][0][0])
                    + hh * 16384;
#pragma unroll
    for (int i = 0; i < 2; ++i)
      gld_lds16(src + (size_t)(rbase + i * 64 + trow) * K + k0 + gsw * 8,
                dstbase + i * 8192 + tid * 16);
  };

  // phase q of tile in slot: quadrant (mh = q>>1, nh = q&1), 16 MFMA
  auto phase = [&](int slot, int q) {
    const int mh = q >> 1, nh = q & 1;
    f16x8 av[4][2], bv[2][2];
#pragma unroll
    for (int m2 = 0; m2 < 4; ++m2) {
      const int R = wr * 128 + (mh * 4 + m2) * 16 + fr;
#pragma unroll
      for (int kk = 0; kk < 2; ++kk)
        av[m2][kk] = *reinterpret_cast<const f16x8*>(
            &As[slot][R][((kk * 4 + g16) ^ (R & 7)) * 8]);
    }
#pragma unroll
    for (int n2 = 0; n2 < 2; ++n2) {
      const int R = wc * 64 + (nh * 2 + n2) * 16 + fr;
#pragma unroll
      for (int kk = 0; kk < 2; ++kk)
        bv[n2][kk] = *reinterpret_cast<const f16x8*>(
            &Bs[slot][R][((kk * 4 + g16) ^ (R & 7)) * 8]);
    }
    asm volatile("s_waitcnt lgkmcnt(0)" ::: "memory");
    __builtin_amdgcn_sched_barrier(0);
    __builtin_amdgcn_s_setprio(1);
#pragma unroll
    for (int kk = 0; kk < 2; ++kk)
#pragma unroll
      for (int m2 = 0; m2 < 4; ++m2)
#pragma unroll
        for (int n2 = 0; n2 < 2; ++n2)
          acc[mh * 4 + m2][nh * 2 + n2] = __builtin_amdgcn_mfma_f32_16x16x32_f16(
              av[m2][kk], bv[n2][kk], acc[mh * 4 + m2][nh * 2 + n2], 0, 0, 0);
    __builtin_amdgcn_s_setprio(0);
  };

  const int T = 12;   // K / 64
  // prologue: all 4 halves of tile 0 -> slot 0 (8 loads/thread)
  stage(0, 0, 0); stage(0, 1, 0); stage(0, 2, 0); stage(0, 3, 0);
  for (int t = 0; t < T; ++t) {
    const int s = t & 1;
    const int k1 = (t + 1) << 6;
    if (t + 1 < T) {
      stage(s ^ 1, 0, k1);   // issue BEFORE wait: stays in flight
      asm volatile("s_waitcnt vmcnt(2)" ::: "memory");
    } else {
      asm volatile("s_waitcnt vmcnt(0)" ::: "memory");
    }
    __builtin_amdgcn_s_barrier();      // entry: tile t landed everywhere;
    __builtin_amdgcn_sched_barrier(0); // prior reads of slot s^1 all done
    phase(s, 0);
    if (t + 1 < T) stage(s ^ 1, 1, k1);
    phase(s, 1);
    if (t + 1 < T) stage(s ^ 1, 2, k1);
    phase(s, 2);
    if (t + 1 < T) stage(s ^ 1, 3, k1);
    phase(s, 3);
    __builtin_amdgcn_s_barrier();      // exit: reads of slot s done
  }

  // ---- fused RoPE epilogue (sec uniform per block: 256 | 768) ----
  const int cl = lane & 15;
  const int rg = lane >> 4;
  const int sec = bn / HH;             // 0=q 1=k 2=v
  f16* dst = (sec == 0) ? Oq : ((sec == 1) ? Ok : Ov);
  const int hb = bn - sec * HH + wc * 64;
#pragma unroll
  for (int m = 0; m < 8; ++m)
#pragma unroll
    for (int r = 0; r < 4; ++r) {
      const int row = bm + wr * 128 + m * 16 + rg * 4 + r;
      if (sec < 2) {
        const int sp = pos[row];
#pragma unroll
        for (int n = 0; n < 4; ++n) {
          const int hd = hb + n * 16 + cl;
          const int d = hd & 63;
          const int d2 = d & 31;
          const float c = ctab[sp * 32 + d2];
          const float sn = stab[sp * 32 + d2];
          float val = acc[m][n][r];
          const float pv = acc[m][n ^ 2][r];
          val = (d < 32) ? (val * c - pv * sn) : (val * c + pv * sn);
          if (sec == 0) val *= 0.125f;
          dst[(size_t)row * HH + hd] = (f16)val;
        }
      } else {
#pragma unroll
        for (int n = 0; n < 4; ++n)
          dst[(size_t)row * HH + hb + n * 16 + cl] = (f16)acc[m][n][r];
      }
    }
}

// ---------------- GEMM2: R10 128^2 kernel (f32 C epilogue) ---------------
__global__ __launch_bounds__(256)
void gemm2_f16(const f16* __restrict__ A, const f16* __restrict__ Bw,
               float* __restrict__ C, int Mtiles, int N, int K) {
  __shared__ __align__(16) f16 As[3][128][32];   // 24 KB
  __shared__ __align__(16) f16 Bs[3][128][32];   // 24 KB
  const int tid = threadIdx.x;
  const int lane = tid & 63;
  const int w = tid >> 6;
  const int wr = w >> 1, wc = w & 1;

  const int bid = blockIdx.x;
  const int xcd = bid & 7;
  const int idx = bid >> 3;
  const int mch = Mtiles >> 3;
  const int bm = (xcd * mch + (idx % mch)) * 128;
  const int bn = (idx / mch) * 128;

  f32x4 acc[4][4] = {};

  const int l4 = lane >> 2;
  const int lk = lane & 3;
  const int srow = w * 32;
  const int fr = lane & 15;
  const int fst = (l4 >> 1) & 3;
  const int pc = (((lane >> 4) ^ ((fr >> 1) & 3)) * 8);

  auto stage = [&](int buf, int k0) {
#pragma unroll
    for (int i = 0; i < 2; ++i) {
      int row = srow + i * 16 + l4;
      gld_lds16(A + (size_t)(bm + row) * K + k0 + (lk ^ fst) * 8,
                (char*)&As[0][0][0] + buf * 8192 + w * 2048 + i * 1024 + lane * 16);
      gld_lds16(Bw + (size_t)(bn + row) * K + k0 + (lk ^ fst) * 8,
                (char*)&Bs[0][0][0] + buf * 8192 + w * 2048 + i * 1024 + lane * 16);
    }
  };
  auto compute = [&](int buf) {
    f16x8 av[4], bv[4];
#pragma unroll
    for (int m = 0; m < 4; ++m)
      av[m] = *reinterpret_cast<const f16x8*>(&As[buf][wr * 64 + m * 16 + fr][pc]);
#pragma unroll
    for (int n = 0; n < 4; ++n)
      bv[n] = *reinterpret_cast<const f16x8*>(&Bs[buf][wc * 64 + n * 16 + fr][pc]);
    __builtin_amdgcn_s_setprio(1);
#pragma unroll
    for (int m = 0; m < 4; ++m)
#pragma unroll
      for (int n = 0; n < 4; ++n)
        acc[m][n] = __builtin_amdgcn_mfma_f32_16x16x32_f16(av[m], bv[n],
                                                           acc[m][n], 0, 0, 0);
    __builtin_amdgcn_s_setprio(0);
  };

  const int T = K >> 5;
  stage(0, 0);
  stage(1, 32);
  for (int t = 0; t < T; ++t) {
    if (t == T - 1)
      asm volatile("s_waitcnt vmcnt(0)" ::: "memory");
    else
      asm volatile("s_waitcnt vmcnt(4)" ::: "memory");
    __builtin_amdgcn_s_barrier();
    __builtin_amdgcn_sched_barrier(0);
    if (t + 2 < T) stage((t + 2) % 3, (t + 2) << 5);
    compute(t % 3);
  }

  const int cl = lane & 15;
  const int rg = lane >> 4;
#pragma unroll
  for (int m = 0; m < 4; ++m)
#pragma unroll
    for (int n = 0; n < 4; ++n)
#pragma unroll
      for (int r = 0; r < 4; ++r) {
        int row = bm + wr * 64 + m * 16 + rg * 4 + r;
        int col = bn + wc * 64 + n * 16 + cl;
        C[(size_t)row * N + col] = acc[m][n][r];
      }
}

// ---------------- MFMA sliding-window attention --------------------------
#define AQT 64
#define AKT 192
#define KP 72
#define VP 200

__global__ __launch_bounds__(256)
void attn_kernel(const f16* __restrict__ qg, const f16* __restrict__ kg,
                 const f16* __restrict__ vg, f16* __restrict__ og) {
  __shared__ __align__(16) f16 Qs[AQT][KP];
  __shared__ __align__(16) f16 Ks[AKT][KP];
  __shared__ __align__(16) f16 Vs[64][VP];
  __shared__ float sums[AQT];

  const int tid = threadIdx.x;
  const int lane = tid & 63;
  const int wq = tid >> 6;
  const int l15 = lane & 15, g = lane >> 4;
  const int blk = blockIdx.x;
  const int qt = blk % (SS / AQT);
  const int h = (blk / (SS / AQT)) % NHEADS;
  const int b = blk / ((SS / AQT) * NHEADS);
  const int q0 = qt * AQT;
  const int kbase = q0 - 64;

#pragma unroll
  for (int i = 0; i < 2; ++i) {
    int idx = tid + i * 256;
    int r = idx >> 3, ch = idx & 7;
    f16x8 v = *reinterpret_cast<const f16x8*>(
        &qg[((size_t)(b * SS + q0 + r)) * HH + h * 64 + ch * 8]);
    *reinterpret_cast<f16x8*>(&Qs[r][ch * 8]) = v;
  }
#pragma unroll
  for (int i = 0; i < 6; ++i) {
    int idx = tid + i * 256;
    int r = idx >> 3, ch = idx & 7;
    int kglob = kbase + r;
    f16x8 v = {};
    if (kglob >= 0 && kglob < SS)
      v = *reinterpret_cast<const f16x8*>(
          &kg[((size_t)(b * SS + kglob)) * HH + h * 64 + ch * 8]);
    *reinterpret_cast<f16x8*>(&Ks[r][ch * 8]) = v;
  }
#pragma unroll
  for (int i = 0; i < 6; ++i) {
    int idx = tid + i * 256;
    int r = idx >> 3, ch = idx & 7;
    int kglob = kbase + r;
    f16x8 v = {};
    if (kglob >= 0 && kglob < SS)
      v = *reinterpret_cast<const f16x8*>(
          &vg[((size_t)(b * SS + kglob)) * HH + h * 64 + ch * 8]);
#pragma unroll
    for (int j = 0; j < 8; ++j) Vs[ch * 8 + j][r] = v[j];
  }
  __syncthreads();

  f32x4 accs[12] = {};
#pragma unroll
  for (int kd = 0; kd < 2; ++kd) {
    f16x8 bq = *reinterpret_cast<const f16x8*>(&Qs[wq * 16 + l15][kd * 32 + g * 8]);
#pragma unroll
    for (int f = 0; f < 12; ++f) {
      f16x8 ak = *reinterpret_cast<const f16x8*>(&Ks[f * 16 + l15][kd * 32 + g * 8]);
      accs[f] = __builtin_amdgcn_mfma_f32_16x16x32_f16(ak, bq, accs[f], 0, 0, 0);
    }
  }
  __syncthreads();

  const int qloc = wq * 16 + l15;
  float mx = -1e30f;
#pragma unroll
  for (int f = 0; f < 12; ++f)
#pragma unroll
    for (int r = 0; r < 4; ++r) {
      int key = f * 16 + g * 4 + r;
      int kglob = kbase + key;
      bool valid = (key >= qloc) && (key <= qloc + 128) && (kglob >= 0) && (kglob < SS);
      float s = valid ? accs[f][r] : -1e30f;
      accs[f][r] = s;
      mx = fmaxf(mx, s);
    }
  mx = fmaxf(mx, __shfl_xor(mx, 16));
  mx = fmaxf(mx, __shfl_xor(mx, 32));
  f16* Ps = &Ks[0][0];
  float sum = 0.f;
#pragma unroll
  for (int f = 0; f < 12; ++f) {
    float p0 = __expf(accs[f][0] - mx);
    float p1 = __expf(accs[f][1] - mx);
    float p2 = __expf(accs[f][2] - mx);
    float p3 = __expf(accs[f][3] - mx);
    sum += (p0 + p1) + (p2 + p3);
    f16x4 pk;
    pk[0] = (f16)p0; pk[1] = (f16)p1; pk[2] = (f16)p2; pk[3] = (f16)p3;
    *reinterpret_cast<f16x4*>(&Ps[(size_t)qloc * VP + f * 16 + g * 4]) = pk;
  }
  sum += __shfl_xor(sum, 16);
  sum += __shfl_xor(sum, 32);
  if (g == 0) sums[qloc] = sum;

  f32x4 acco[4] = {};
#pragma unroll
  for (int ks = 0; ks < 6; ++ks) {
    f16x8 pa = *reinterpret_cast<const f16x8*>(&Ps[(size_t)(wq * 16 + l15) * VP + ks * 32 + g * 8]);
#pragma unroll
    for (int n = 0; n < 4; ++n) {
      f16x8 bv = *reinterpret_cast<const f16x8*>(&Vs[n * 16 + l15][ks * 32 + g * 8]);
      acco[n] = __builtin_amdgcn_mfma_f32_16x16x32_f16(pa, bv, acco[n], 0, 0, 0);
    }
  }
#pragma unroll
  for (int r = 0; r < 4; ++r) {
    int qo = wq * 16 + g * 4 + r;
    float inv = 1.0f / sums[qo];
    size_t base = ((size_t)(b * SS + q0 + qo)) * HH + h * 64;
#pragma unroll
    for (int n = 0; n < 4; ++n)
      og[base + n * 16 + l15] = (f16)(acco[n][r] * inv);
  }
}

extern "C" void kernel_launch(void* const* d_in, const int* in_sizes, int n_in,
                              void* d_out, int out_size, void* d_ws, size_t ws_size,
                              hipStream_t stream) {
  const float* hs = (const float*)d_in[0];
  const int* pos = (const int*)d_in[3];
  const float* Wqkv = (const float*)d_in[4];
  const float* Wo = (const float*)d_in[5];
  float* out = (float*)d_out;

  uint8_t* ws = (uint8_t*)d_ws;
  size_t off = 0;
  float* ctab = (float*)(ws + off); off += (size_t)SS * 32 * 4;
  float* stab = (float*)(ws + off); off += (size_t)SS * 32 * 4;
  f16* hs16 = (f16*)(ws + off); off += (size_t)MTOT * HH * 2;
  f16* wq16 = (f16*)(ws + off); off += (size_t)NQKV * HH * 2;
  f16* wo16 = (f16*)(ws + off); off += (size_t)HH * HH * 2;
  f16* qf = (f16*)(ws + off); off += (size_t)MTOT * HH * 2;
  f16* kf = (f16*)(ws + off); off += (size_t)MTOT * HH * 2;
  f16* vf = (f16*)(ws + off); off += (size_t)MTOT * HH * 2;
  f16* af = (f16*)(ws + off); off += (size_t)MTOT * HH * 2;

  cvt_kernel<<<(MTOT * HH / 4 + 255) / 256, 256, 0, stream>>>(hs, hs16, MTOT * HH / 4);
  cvt_kernel<<<(NQKV * HH / 4 + 255) / 256, 256, 0, stream>>>(Wqkv, wq16, NQKV * HH / 4);
  cvt_kernel<<<(HH * HH / 4 + 255) / 256, 256, 0, stream>>>(Wo, wo16, HH * HH / 4);
  rope_table_kernel<<<(SS * 32 + 255) / 256, 256, 0, stream>>>(ctab, stab);

  // 1. QKV projection + fused RoPE/scale (256^2, 8-wave, phase-split)
  gemm1_256<<<(MTOT / 256) * (NQKV / 256), 512, 0, stream>>>(
      hs16, wq16, qf, kf, vf, pos, ctab, stab);
  // 2. Attention
  attn_kernel<<<BB * NHEADS * (SS / AQT), 256, 0, stream>>>(qf, kf, vf, af);
  // 3. Output projection (R10 128^2 kernel)
  gemm2_f16<<<(MTOT / 128) * (HH / 128), 256, 0, stream>>>(
      af, wo16, out, MTOT / 128, HH, HH);
}

// Round 13
// 115.671 us; speedup vs baseline: 1.1562x; 1.1562x over previous
//
#include <hip/hip_runtime.h>
#include <hip/hip_bf16.h>
#include <math.h>

#define BB 2
#define SS 4096
#define HH 768
#define NHEADS 12
#define MTOT (BB*SS)     // 8192
#define NQKV (3*HH)      // 2304

typedef _Float16 f16;
typedef __attribute__((ext_vector_type(8))) _Float16 f16x8;
typedef __attribute__((ext_vector_type(4))) _Float16 f16x4;
typedef __attribute__((ext_vector_type(4))) float f32x4;

__device__ __forceinline__ void gld_lds16(const void* g, void* l) {
  __builtin_amdgcn_global_load_lds(
      (const __attribute__((address_space(1))) unsigned int*)g,
      (__attribute__((address_space(3))) unsigned int*)l, 16, 0, 0);
}

// ---------------- merged f32 -> f16 convert (one launch for all 3) -------
__global__ __launch_bounds__(256)
void cvt_all(const float* __restrict__ hs, const float* __restrict__ wq,
             const float* __restrict__ wo, f16* __restrict__ hs16,
             f16* __restrict__ wq16, f16* __restrict__ wo16) {
  const int n1 = MTOT * HH / 4, n2 = NQKV * HH / 4, n3 = HH * HH / 4;
  int i = blockIdx.x * 256 + threadIdx.x;
  const float* src;
  f16* dst;
  int j = i;
  if (i < n1) { src = hs; dst = hs16; }
  else if (i < n1 + n2) { src = wq; dst = wq16; j = i - n1; }
  else if (i < n1 + n2 + n3) { src = wo; dst = wo16; j = i - n1 - n2; }
  else return;
  float4 v = reinterpret_cast<const float4*>(src)[j];
  f16x4 o;
  o[0] = (f16)v.x; o[1] = (f16)v.y; o[2] = (f16)v.z; o[3] = (f16)v.w;
  reinterpret_cast<f16x4*>(dst)[j] = o;
}

// ---------------- RoPE cos/sin table (f64 phase) -------------------------
__global__ void rope_table_kernel(float* __restrict__ ctab, float* __restrict__ stab) {
  int idx = blockIdx.x * 256 + threadIdx.x;   // 4096*32
  if (idx >= SS * 32) return;
  int s = idx >> 5;
  int j = idx & 31;
  const double r = 0.7498942093324559;  // 10000^(-1/32)
  double inv = 1.0;
  for (int t = 0; t < j; ++t) inv *= r;
  double ph = (double)s * inv;
  const double TWO_PI = 6.283185307179586;
  double red = ph - TWO_PI * floor(ph / TWO_PI);
  float rf = (float)red;
  ctab[idx] = cosf(rf);
  stab[idx] = sinf(rf);
}

// ---------------- f16 MFMA GEMM (R10 winner, verbatim) -------------------
// BK=32, 3-buffer, ONE barrier/step, counted vmcnt, chunk swizzle,
// M-chunked XCD map (FETCH 94->27 MB verified R10).
template<int EPI>
__global__ __launch_bounds__(256)
void gemm_f16(const f16* __restrict__ A, const f16* __restrict__ Bw,
              float* __restrict__ C,
              f16* __restrict__ Oq, f16* __restrict__ Ok, f16* __restrict__ Ov,
              const int* __restrict__ pos,
              const float* __restrict__ ctab, const float* __restrict__ stab,
              int Mtiles, int N, int K) {
  __shared__ __align__(16) f16 As[3][128][32];   // 24 KB
  __shared__ __align__(16) f16 Bs[3][128][32];   // 24 KB
  const int tid = threadIdx.x;
  const int lane = tid & 63;
  const int w = tid >> 6;
  const int wr = w >> 1, wc = w & 1;

  const int bid = blockIdx.x;
  const int xcd = bid & 7;
  const int idx = bid >> 3;
  const int mch = Mtiles >> 3;                 // 8 M-tiles per XCD chunk
  const int bm = (xcd * mch + (idx % mch)) * 128;
  const int bn = (idx / mch) * 128;

  f32x4 acc[4][4] = {};

  const int l4 = lane >> 2;
  const int lk = lane & 3;
  const int srow = w * 32;
  const int fr = lane & 15;
  const int fst = (l4 >> 1) & 3;
  const int pc = (((lane >> 4) ^ ((fr >> 1) & 3)) * 8);

  auto stage = [&](int buf, int k0) {
#pragma unroll
    for (int i = 0; i < 2; ++i) {
      int row = srow + i * 16 + l4;
      gld_lds16(A + (size_t)(bm + row) * K + k0 + (lk ^ fst) * 8,
                (char*)&As[0][0][0] + buf * 8192 + w * 2048 + i * 1024 + lane * 16);
      gld_lds16(Bw + (size_t)(bn + row) * K + k0 + (lk ^ fst) * 8,
                (char*)&Bs[0][0][0] + buf * 8192 + w * 2048 + i * 1024 + lane * 16);
    }
  };
  auto compute = [&](int buf) {
    f16x8 av[4], bv[4];
#pragma unroll
    for (int m = 0; m < 4; ++m)
      av[m] = *reinterpret_cast<const f16x8*>(&As[buf][wr * 64 + m * 16 + fr][pc]);
#pragma unroll
    for (int n = 0; n < 4; ++n)
      bv[n] = *reinterpret_cast<const f16x8*>(&Bs[buf][wc * 64 + n * 16 + fr][pc]);
    __builtin_amdgcn_s_setprio(1);
#pragma unroll
    for (int m = 0; m < 4; ++m)
#pragma unroll
      for (int n = 0; n < 4; ++n)
        acc[m][n] = __builtin_amdgcn_mfma_f32_16x16x32_f16(av[m], bv[n],
                                                           acc[m][n], 0, 0, 0);
    __builtin_amdgcn_s_setprio(0);
  };

  const int T = K >> 5;   // 24 for K=768
  stage(0, 0);
  stage(1, 32);
  for (int t = 0; t < T; ++t) {
    if (t == T - 1)
      asm volatile("s_waitcnt vmcnt(0)" ::: "memory");
    else
      asm volatile("s_waitcnt vmcnt(4)" ::: "memory");
    __builtin_amdgcn_s_barrier();
    __builtin_amdgcn_sched_barrier(0);
    if (t + 2 < T) stage((t + 2) % 3, (t + 2) << 5);
    compute(t % 3);
  }

  const int cl = lane & 15;
  const int rg = lane >> 4;
  if (EPI == 0) {
#pragma unroll
    for (int m = 0; m < 4; ++m)
#pragma unroll
      for (int n = 0; n < 4; ++n)
#pragma unroll
        for (int r = 0; r < 4; ++r) {
          int row = bm + wr * 64 + m * 16 + rg * 4 + r;
          int col = bn + wc * 64 + n * 16 + cl;
          C[(size_t)row * N + col] = acc[m][n][r];
        }
  } else {
    const int sec = bn / HH;        // 0=q 1=k 2=v (uniform per block)
    f16* dst = (sec == 0) ? Oq : ((sec == 1) ? Ok : Ov);
    const int hb = bn - sec * HH + wc * 64;
#pragma unroll
    for (int m = 0; m < 4; ++m)
#pragma unroll
      for (int r = 0; r < 4; ++r) {
        int row = bm + wr * 64 + m * 16 + rg * 4 + r;
        if (sec < 2) {
          int s = pos[row];
#pragma unroll
          for (int n = 0; n < 4; ++n) {
            int hd = hb + n * 16 + cl;
            int d = hd & 63;
            int d2 = d & 31;
            float c = ctab[s * 32 + d2];
            float sn = stab[s * 32 + d2];
            float val = acc[m][n][r];
            float pv = acc[m][n ^ 2][r];
            val = (d < 32) ? (val * c - pv * sn) : (val * c + pv * sn);
            if (sec == 0) val *= 0.125f;
            dst[(size_t)row * HH + hd] = (f16)val;
          }
        } else {
#pragma unroll
          for (int n = 0; n < 4; ++n)
            dst[(size_t)row * HH + hb + n * 16 + cl] = (f16)acc[m][n][r];
        }
      }
  }
}

// ---------------- MFMA sliding-window attention --------------------------
// Block: (b, h, 64-query tile). Window keys: [q0-64, q0+127] = 192 rows.
// qt-contiguous XCD map: each XCD owns 192 consecutive (qt-major) blocks
// = 3 whole (b,h) panels -> K/V window overlap between adjacent q-tiles
// is served from that XCD's L2 (same mechanism as the GEMM fix, R10).
#define AQT 64
#define AKT 192
#define KP 72     // K/Q row pad (f16): 144 B rows
#define VP 200    // Vt / P row pad: 400 B rows

__global__ __launch_bounds__(256)
void attn_kernel(const f16* __restrict__ qg, const f16* __restrict__ kg,
                 const f16* __restrict__ vg, f16* __restrict__ og) {
  __shared__ __align__(16) f16 Qs[AQT][KP];     // 9216 B
  __shared__ __align__(16) f16 Ks[AKT][KP];     // 27648 B, reused for P[64][VP]
  __shared__ __align__(16) f16 Vs[64][VP];      // 25600 B (transposed V)
  __shared__ float sums[AQT];

  const int tid = threadIdx.x;
  const int lane = tid & 63;
  const int wq = tid >> 6;
  const int l15 = lane & 15, g = lane >> 4;
  // grid = 1536 = 8 XCDs x 192; decode qt-fastest within each XCD chunk
  const int lin = (blockIdx.x & 7) * 192 + (blockIdx.x >> 3);
  const int qt = lin & 63;
  const int h = (lin >> 6) % NHEADS;
  const int b = lin / (64 * NHEADS);
  const int q0 = qt * AQT;
  const int kbase = q0 - 64;

  // ---- stage Q (64x64), K (192x64), V transposed (64x192) ----
#pragma unroll
  for (int i = 0; i < 2; ++i) {
    int idx = tid + i * 256;
    int r = idx >> 3, ch = idx & 7;
    f16x8 v = *reinterpret_cast<const f16x8*>(
        &qg[((size_t)(b * SS + q0 + r)) * HH + h * 64 + ch * 8]);
    *reinterpret_cast<f16x8*>(&Qs[r][ch * 8]) = v;
  }
#pragma unroll
  for (int i = 0; i < 6; ++i) {
    int idx = tid + i * 256;
    int r = idx >> 3, ch = idx & 7;
    int kglob = kbase + r;
    f16x8 v = {};
    if (kglob >= 0 && kglob < SS)
      v = *reinterpret_cast<const f16x8*>(
          &kg[((size_t)(b * SS + kglob)) * HH + h * 64 + ch * 8]);
    *reinterpret_cast<f16x8*>(&Ks[r][ch * 8]) = v;
  }
#pragma unroll
  for (int i = 0; i < 6; ++i) {
    int idx = tid + i * 256;
    int r = idx >> 3, ch = idx & 7;
    int kglob = kbase + r;
    f16x8 v = {};
    if (kglob >= 0 && kglob < SS)
      v = *reinterpret_cast<const f16x8*>(
          &vg[((size_t)(b * SS + kglob)) * HH + h * 64 + ch * 8]);
#pragma unroll
    for (int j = 0; j < 8; ++j) Vs[ch * 8 + j][r] = v[j];
  }
  __syncthreads();

  // ---- S^T = K . Q^T ----
  f32x4 accs[12] = {};
#pragma unroll
  for (int kd = 0; kd < 2; ++kd) {
    f16x8 bq = *reinterpret_cast<const f16x8*>(&Qs[wq * 16 + l15][kd * 32 + g * 8]);
#pragma unroll
    for (int f = 0; f < 12; ++f) {
      f16x8 ak = *reinterpret_cast<const f16x8*>(&Ks[f * 16 + l15][kd * 32 + g * 8]);
      accs[f] = __builtin_amdgcn_mfma_f32_16x16x32_f16(ak, bq, accs[f], 0, 0, 0);
    }
  }
  __syncthreads();   // Ks becomes P storage

  // ---- softmax over keys; lane owns column q = wq*16+l15 ----
  const int qloc = wq * 16 + l15;
  float mx = -1e30f;
#pragma unroll
  for (int f = 0; f < 12; ++f)
#pragma unroll
    for (int r = 0; r < 4; ++r) {
      int key = f * 16 + g * 4 + r;
      int kglob = kbase + key;
      bool valid = (key >= qloc) && (key <= qloc + 128) && (kglob >= 0) && (kglob < SS);
      float s = valid ? accs[f][r] : -1e30f;
      accs[f][r] = s;
      mx = fmaxf(mx, s);
    }
  mx = fmaxf(mx, __shfl_xor(mx, 16));
  mx = fmaxf(mx, __shfl_xor(mx, 32));
  f16* Ps = &Ks[0][0];
  float sum = 0.f;
#pragma unroll
  for (int f = 0; f < 12; ++f) {
    float p0 = __expf(accs[f][0] - mx);
    float p1 = __expf(accs[f][1] - mx);
    float p2 = __expf(accs[f][2] - mx);
    float p3 = __expf(accs[f][3] - mx);
    sum += (p0 + p1) + (p2 + p3);
    f16x4 pk;
    pk[0] = (f16)p0; pk[1] = (f16)p1; pk[2] = (f16)p2; pk[3] = (f16)p3;
    *reinterpret_cast<f16x4*>(&Ps[(size_t)qloc * VP + f * 16 + g * 4]) = pk;
  }
  sum += __shfl_xor(sum, 16);
  sum += __shfl_xor(sum, 32);
  if (g == 0) sums[qloc] = sum;

  // ---- O = P . V ----
  f32x4 acco[4] = {};
#pragma unroll
  for (int ks = 0; ks < 6; ++ks) {
    f16x8 pa = *reinterpret_cast<const f16x8*>(&Ps[(size_t)(wq * 16 + l15) * VP + ks * 32 + g * 8]);
#pragma unroll
    for (int n = 0; n < 4; ++n) {
      f16x8 bv = *reinterpret_cast<const f16x8*>(&Vs[n * 16 + l15][ks * 32 + g * 8]);
      acco[n] = __builtin_amdgcn_mfma_f32_16x16x32_f16(pa, bv, acco[n], 0, 0, 0);
    }
  }
#pragma unroll
  for (int r = 0; r < 4; ++r) {
    int qo = wq * 16 + g * 4 + r;
    float inv = 1.0f / sums[qo];
    size_t base = ((size_t)(b * SS + q0 + qo)) * HH + h * 64;
#pragma unroll
    for (int n = 0; n < 4; ++n)
      og[base + n * 16 + l15] = (f16)(acco[n][r] * inv);
  }
}

extern "C" void kernel_launch(void* const* d_in, const int* in_sizes, int n_in,
                              void* d_out, int out_size, void* d_ws, size_t ws_size,
                              hipStream_t stream) {
  const float* hs = (const float*)d_in[0];
  const int* pos = (const int*)d_in[3];
  const float* Wqkv = (const float*)d_in[4];
  const float* Wo = (const float*)d_in[5];
  float* out = (float*)d_out;

  uint8_t* ws = (uint8_t*)d_ws;
  size_t off = 0;
  float* ctab = (float*)(ws + off); off += (size_t)SS * 32 * 4;
  float* stab = (float*)(ws + off); off += (size_t)SS * 32 * 4;
  f16* hs16 = (f16*)(ws + off); off += (size_t)MTOT * HH * 2;
  f16* wq16 = (f16*)(ws + off); off += (size_t)NQKV * HH * 2;
  f16* wo16 = (f16*)(ws + off); off += (size_t)HH * HH * 2;
  f16* qf = (f16*)(ws + off); off += (size_t)MTOT * HH * 2;
  f16* kf = (f16*)(ws + off); off += (size_t)MTOT * HH * 2;
  f16* vf = (f16*)(ws + off); off += (size_t)MTOT * HH * 2;
  f16* af = (f16*)(ws + off); off += (size_t)MTOT * HH * 2;

  const int ncvt = (MTOT * HH + NQKV * HH + HH * HH) / 4;
  cvt_all<<<(ncvt + 255) / 256, 256, 0, stream>>>(hs, Wqkv, Wo, hs16, wq16, wo16);
  rope_table_kernel<<<(SS * 32 + 255) / 256, 256, 0, stream>>>(ctab, stab);

  // 1. QKV projection + fused RoPE/scale -> q/k/v f16
  gemm_f16<1><<<(MTOT / 128) * (NQKV / 128), 256, 0, stream>>>(
      hs16, wq16, nullptr, qf, kf, vf, pos, ctab, stab, MTOT / 128, NQKV, HH);
  // 2. Attention (qt-contiguous XCD map)
  attn_kernel<<<BB * NHEADS * (SS / AQT), 256, 0, stream>>>(qf, kf, vf, af);
  // 3. Output projection
  gemm_f16<0><<<(MTOT / 128) * (HH / 128), 256, 0, stream>>>(
      af, wo16, out, nullptr, nullptr, nullptr, nullptr, nullptr, nullptr,
      MTOT / 128, HH, HH);
}

// Round 14
// 108.746 us; speedup vs baseline: 1.2299x; 1.0637x over previous
//
#include <hip/hip_runtime.h>
#include <hip/hip_bf16.h>
#include <math.h>

#define BB 2
#define SS 4096
#define HH 768
#define NHEADS 12
#define MTOT (BB*SS)     // 8192
#define NQKV (3*HH)      // 2304

typedef _Float16 f16;
typedef __attribute__((ext_vector_type(8))) _Float16 f16x8;
typedef __attribute__((ext_vector_type(4))) _Float16 f16x4;
typedef __attribute__((ext_vector_type(4))) float f32x4;

__device__ __forceinline__ void gld_lds16(const void* g, void* l) {
  __builtin_amdgcn_global_load_lds(
      (const __attribute__((address_space(1))) unsigned int*)g,
      (__attribute__((address_space(3))) unsigned int*)l, 16, 0, 0);
}

// ---------------- merged f32 -> f16 convert (one launch for all 3) -------
__global__ __launch_bounds__(256)
void cvt_all(const float* __restrict__ hs, const float* __restrict__ wq,
             const float* __restrict__ wo, f16* __restrict__ hs16,
             f16* __restrict__ wq16, f16* __restrict__ wo16) {
  const int n1 = MTOT * HH / 4, n2 = NQKV * HH / 4, n3 = HH * HH / 4;
  int i = blockIdx.x * 256 + threadIdx.x;
  const float* src;
  f16* dst;
  int j = i;
  if (i < n1) { src = hs; dst = hs16; }
  else if (i < n1 + n2) { src = wq; dst = wq16; j = i - n1; }
  else if (i < n1 + n2 + n3) { src = wo; dst = wo16; j = i - n1 - n2; }
  else return;
  float4 v = reinterpret_cast<const float4*>(src)[j];
  f16x4 o;
  o[0] = (f16)v.x; o[1] = (f16)v.y; o[2] = (f16)v.z; o[3] = (f16)v.w;
  reinterpret_cast<f16x4*>(dst)[j] = o;
}

// ---------------- RoPE cos/sin table (f64 phase) -------------------------
__global__ void rope_table_kernel(float* __restrict__ ctab, float* __restrict__ stab) {
  int idx = blockIdx.x * 256 + threadIdx.x;   // 4096*32
  if (idx >= SS * 32) return;
  int s = idx >> 5;
  int j = idx & 31;
  const double r = 0.7498942093324559;  // 10000^(-1/32)
  double inv = 1.0;
  for (int t = 0; t < j; ++t) inv *= r;
  double ph = (double)s * inv;
  const double TWO_PI = 6.283185307179586;
  double red = ph - TWO_PI * floor(ph / TWO_PI);
  float rf = (float)red;
  ctab[idx] = cosf(rf);
  stab[idx] = sinf(rf);
}

// ---------------- f16 MFMA GEMM (R10 winner, verbatim) -------------------
template<int EPI>
__global__ __launch_bounds__(256)
void gemm_f16(const f16* __restrict__ A, const f16* __restrict__ Bw,
              float* __restrict__ C,
              f16* __restrict__ Oq, f16* __restrict__ Ok, f16* __restrict__ Ov,
              const int* __restrict__ pos,
              const float* __restrict__ ctab, const float* __restrict__ stab,
              int Mtiles, int N, int K) {
  __shared__ __align__(16) f16 As[3][128][32];   // 24 KB
  __shared__ __align__(16) f16 Bs[3][128][32];   // 24 KB
  const int tid = threadIdx.x;
  const int lane = tid & 63;
  const int w = tid >> 6;
  const int wr = w >> 1, wc = w & 1;

  const int bid = blockIdx.x;
  const int xcd = bid & 7;
  const int idx = bid >> 3;
  const int mch = Mtiles >> 3;                 // 8 M-tiles per XCD chunk
  const int bm = (xcd * mch + (idx % mch)) * 128;
  const int bn = (idx / mch) * 128;

  f32x4 acc[4][4] = {};

  const int l4 = lane >> 2;
  const int lk = lane & 3;
  const int srow = w * 32;
  const int fr = lane & 15;
  const int fst = (l4 >> 1) & 3;
  const int pc = (((lane >> 4) ^ ((fr >> 1) & 3)) * 8);

  auto stage = [&](int buf, int k0) {
#pragma unroll
    for (int i = 0; i < 2; ++i) {
      int row = srow + i * 16 + l4;
      gld_lds16(A + (size_t)(bm + row) * K + k0 + (lk ^ fst) * 8,
                (char*)&As[0][0][0] + buf * 8192 + w * 2048 + i * 1024 + lane * 16);
      gld_lds16(Bw + (size_t)(bn + row) * K + k0 + (lk ^ fst) * 8,
                (char*)&Bs[0][0][0] + buf * 8192 + w * 2048 + i * 1024 + lane * 16);
    }
  };
  auto compute = [&](int buf) {
    f16x8 av[4], bv[4];
#pragma unroll
    for (int m = 0; m < 4; ++m)
      av[m] = *reinterpret_cast<const f16x8*>(&As[buf][wr * 64 + m * 16 + fr][pc]);
#pragma unroll
    for (int n = 0; n < 4; ++n)
      bv[n] = *reinterpret_cast<const f16x8*>(&Bs[buf][wc * 64 + n * 16 + fr][pc]);
    __builtin_amdgcn_s_setprio(1);
#pragma unroll
    for (int m = 0; m < 4; ++m)
#pragma unroll
      for (int n = 0; n < 4; ++n)
        acc[m][n] = __builtin_amdgcn_mfma_f32_16x16x32_f16(av[m], bv[n],
                                                           acc[m][n], 0, 0, 0);
    __builtin_amdgcn_s_setprio(0);
  };

  const int T = K >> 5;   // 24 for K=768
  stage(0, 0);
  stage(1, 32);
  for (int t = 0; t < T; ++t) {
    if (t == T - 1)
      asm volatile("s_waitcnt vmcnt(0)" ::: "memory");
    else
      asm volatile("s_waitcnt vmcnt(4)" ::: "memory");
    __builtin_amdgcn_s_barrier();
    __builtin_amdgcn_sched_barrier(0);
    if (t + 2 < T) stage((t + 2) % 3, (t + 2) << 5);
    compute(t % 3);
  }

  const int cl = lane & 15;
  const int rg = lane >> 4;
  if (EPI == 0) {
#pragma unroll
    for (int m = 0; m < 4; ++m)
#pragma unroll
      for (int n = 0; n < 4; ++n)
#pragma unroll
        for (int r = 0; r < 4; ++r) {
          int row = bm + wr * 64 + m * 16 + rg * 4 + r;
          int col = bn + wc * 64 + n * 16 + cl;
          C[(size_t)row * N + col] = acc[m][n][r];
        }
  } else {
    const int sec = bn / HH;        // 0=q 1=k 2=v (uniform per block)
    f16* dst = (sec == 0) ? Oq : ((sec == 1) ? Ok : Ov);
    const int hb = bn - sec * HH + wc * 64;
#pragma unroll
    for (int m = 0; m < 4; ++m)
#pragma unroll
      for (int r = 0; r < 4; ++r) {
        int row = bm + wr * 64 + m * 16 + rg * 4 + r;
        if (sec < 2) {
          int s = pos[row];
#pragma unroll
          for (int n = 0; n < 4; ++n) {
            int hd = hb + n * 16 + cl;
            int d = hd & 63;
            int d2 = d & 31;
            float c = ctab[s * 32 + d2];
            float sn = stab[s * 32 + d2];
            float val = acc[m][n][r];
            float pv = acc[m][n ^ 2][r];
            val = (d < 32) ? (val * c - pv * sn) : (val * c + pv * sn);
            if (sec == 0) val *= 0.125f;
            dst[(size_t)row * HH + hd] = (f16)val;
          }
        } else {
#pragma unroll
          for (int n = 0; n < 4; ++n)
            dst[(size_t)row * HH + hb + n * 16 + cl] = (f16)acc[m][n][r];
        }
      }
  }
}

// ---------------- MFMA sliding-window attention --------------------------
// Block: (b, h, 64-query tile). Window keys: [q0-64, q0+127] = 192 rows.
// qt-contiguous XCD map (R13). Q lives in registers (no Qs buffer).
// Vs[64][192] holds V^T with 16B-chunk swizzle c' = c ^ (row&7) ^ ((row>>3)&7):
// transpose-scatter writes hit 32 banks at 2 lanes each (free, was 16-way);
// PV reads 2-way (free). LDS 52.5 KB -> 3 blocks/CU.
#define AQT 64
#define AKT 192
#define KP 72     // K row pad (f16): 144 B rows
#define VPP 200   // P row stride (f16) inside Ks region

__global__ __launch_bounds__(256)
void attn_kernel(const f16* __restrict__ qg, const f16* __restrict__ kg,
                 const f16* __restrict__ vg, f16* __restrict__ og) {
  __shared__ __align__(16) f16 Ks[AKT][KP];     // 27648 B, reused for P[64][VPP]
  __shared__ __align__(16) f16 Vs[64][192];     // 24576 B (transposed V, swizzled)
  __shared__ float sums[AQT];

  const int tid = threadIdx.x;
  const int lane = tid & 63;
  const int wq = tid >> 6;
  const int l15 = lane & 15, g = lane >> 4;
  // grid = 1536 = 8 XCDs x 192; decode qt-fastest within each XCD chunk
  const int lin = (blockIdx.x & 7) * 192 + (blockIdx.x >> 3);
  const int qt = lin & 63;
  const int h = (lin >> 6) % NHEADS;
  const int b = lin / (64 * NHEADS);
  const int q0 = qt * AQT;
  const int kbase = q0 - 64;

  // ---- Q straight to registers (scale folded at GEMM1) ----
  const size_t qrow = ((size_t)(b * SS + q0 + wq * 16 + l15)) * HH + h * 64;
  const f16x8 bq0 = *reinterpret_cast<const f16x8*>(&qg[qrow + g * 8]);
  const f16x8 bq1 = *reinterpret_cast<const f16x8*>(&qg[qrow + 32 + g * 8]);

  // ---- stage K (192x64) vectorized; V transposed+swizzled ----
#pragma unroll
  for (int i = 0; i < 6; ++i) {
    int idx = tid + i * 256;
    int r = idx >> 3, ch = idx & 7;
    int kglob = kbase + r;
    f16x8 v = {};
    if (kglob >= 0 && kglob < SS)
      v = *reinterpret_cast<const f16x8*>(
          &kg[((size_t)(b * SS + kglob)) * HH + h * 64 + ch * 8]);
    *reinterpret_cast<f16x8*>(&Ks[r][ch * 8]) = v;
  }
#pragma unroll
  for (int i = 0; i < 6; ++i) {
    int idx = tid + i * 256;
    int r = idx >> 3, ch = idx & 7;
    int kglob = kbase + r;
    f16x8 v = {};
    if (kglob >= 0 && kglob < SS)
      v = *reinterpret_cast<const f16x8*>(
          &vg[((size_t)(b * SS + kglob)) * HH + h * 64 + ch * 8]);
    const int c = r >> 3, o = r & 7;
#pragma unroll
    for (int j = 0; j < 8; ++j) {
      const int row = ch * 8 + j;
      const int cp = c ^ (row & 7) ^ ((row >> 3) & 7);
      Vs[row][cp * 8 + o] = v[j];
    }
  }
  __syncthreads();

  // ---- S^T = K . Q^T ----
  f32x4 accs[12] = {};
#pragma unroll
  for (int f = 0; f < 12; ++f) {
    f16x8 ak = *reinterpret_cast<const f16x8*>(&Ks[f * 16 + l15][g * 8]);
    accs[f] = __builtin_amdgcn_mfma_f32_16x16x32_f16(ak, bq0, accs[f], 0, 0, 0);
  }
#pragma unroll
  for (int f = 0; f < 12; ++f) {
    f16x8 ak = *reinterpret_cast<const f16x8*>(&Ks[f * 16 + l15][32 + g * 8]);
    accs[f] = __builtin_amdgcn_mfma_f32_16x16x32_f16(ak, bq1, accs[f], 0, 0, 0);
  }
  __syncthreads();   // Ks becomes P storage

  // ---- softmax over keys; lane owns column q = wq*16+l15 ----
  const int qloc = wq * 16 + l15;
  float mx = -1e30f;
#pragma unroll
  for (int f = 0; f < 12; ++f)
#pragma unroll
    for (int r = 0; r < 4; ++r) {
      int key = f * 16 + g * 4 + r;
      int kglob = kbase + key;
      bool valid = (key >= qloc) && (key <= qloc + 128) && (kglob >= 0) && (kglob < SS);
      float s = valid ? accs[f][r] : -1e30f;
      accs[f][r] = s;
      mx = fmaxf(mx, s);
    }
  mx = fmaxf(mx, __shfl_xor(mx, 16));
  mx = fmaxf(mx, __shfl_xor(mx, 32));
  f16* Ps = &Ks[0][0];
  float sum = 0.f;
#pragma unroll
  for (int f = 0; f < 12; ++f) {
    float p0 = __expf(accs[f][0] - mx);
    float p1 = __expf(accs[f][1] - mx);
    float p2 = __expf(accs[f][2] - mx);
    float p3 = __expf(accs[f][3] - mx);
    sum += (p0 + p1) + (p2 + p3);
    f16x4 pk;
    pk[0] = (f16)p0; pk[1] = (f16)p1; pk[2] = (f16)p2; pk[3] = (f16)p3;
    *reinterpret_cast<f16x4*>(&Ps[(size_t)qloc * VPP + f * 16 + g * 4]) = pk;
  }
  sum += __shfl_xor(sum, 16);
  sum += __shfl_xor(sum, 32);
  if (g == 0) sums[qloc] = sum;

  // ---- O = P . V ----
  f32x4 acco[4] = {};
#pragma unroll
  for (int ks = 0; ks < 6; ++ks) {
    f16x8 pa = *reinterpret_cast<const f16x8*>(&Ps[(size_t)(wq * 16 + l15) * VPP + ks * 32 + g * 8]);
#pragma unroll
    for (int n = 0; n < 4; ++n) {
      const int row = n * 16 + l15;
      const int cp = (4 * ks + g) ^ (row & 7) ^ ((row >> 3) & 7);
      f16x8 bv = *reinterpret_cast<const f16x8*>(&Vs[row][cp * 8]);
      acco[n] = __builtin_amdgcn_mfma_f32_16x16x32_f16(pa, bv, acco[n], 0, 0, 0);
    }
  }
#pragma unroll
  for (int r = 0; r < 4; ++r) {
    int qo = wq * 16 + g * 4 + r;
    float inv = 1.0f / sums[qo];
    size_t base = ((size_t)(b * SS + q0 + qo)) * HH + h * 64;
#pragma unroll
    for (int n = 0; n < 4; ++n)
      og[base + n * 16 + l15] = (f16)(acco[n][r] * inv);
  }
}

extern "C" void kernel_launch(void* const* d_in, const int* in_sizes, int n_in,
                              void* d_out, int out_size, void* d_ws, size_t ws_size,
                              hipStream_t stream) {
  const float* hs = (const float*)d_in[0];
  const int* pos = (const int*)d_in[3];
  const float* Wqkv = (const float*)d_in[4];
  const float* Wo = (const float*)d_in[5];
  float* out = (float*)d_out;

  uint8_t* ws = (uint8_t*)d_ws;
  size_t off = 0;
  float* ctab = (float*)(ws + off); off += (size_t)SS * 32 * 4;
  float* stab = (float*)(ws + off); off += (size_t)SS * 32 * 4;
  f16* hs16 = (f16*)(ws + off); off += (size_t)MTOT * HH * 2;
  f16* wq16 = (f16*)(ws + off); off += (size_t)NQKV * HH * 2;
  f16* wo16 = (f16*)(ws + off); off += (size_t)HH * HH * 2;
  f16* qf = (f16*)(ws + off); off += (size_t)MTOT * HH * 2;
  f16* kf = (f16*)(ws + off); off += (size_t)MTOT * HH * 2;
  f16* vf = (f16*)(ws + off); off += (size_t)MTOT * HH * 2;
  f16* af = (f16*)(ws + off); off += (size_t)MTOT * HH * 2;

  const int ncvt = (MTOT * HH + NQKV * HH + HH * HH) / 4;
  cvt_all<<<(ncvt + 255) / 256, 256, 0, stream>>>(hs, Wqkv, Wo, hs16, wq16, wo16);
  rope_table_kernel<<<(SS * 32 + 255) / 256, 256, 0, stream>>>(ctab, stab);

  // 1. QKV projection + fused RoPE/scale -> q/k/v f16
  gemm_f16<1><<<(MTOT / 128) * (NQKV / 128), 256, 0, stream>>>(
      hs16, wq16, nullptr, qf, kf, vf, pos, ctab, stab, MTOT / 128, NQKV, HH);
  // 2. Attention (qt-contiguous XCD map; swizzled V, Q in regs)
  attn_kernel<<<BB * NHEADS * (SS / AQT), 256, 0, stream>>>(qf, kf, vf, af);
  // 3. Output projection
  gemm_f16<0><<<(MTOT / 128) * (HH / 128), 256, 0, stream>>>(
      af, wo16, out, nullptr, nullptr, nullptr, nullptr, nullptr, nullptr,
      MTOT / 128, HH, HH);
}